// Round 10
// baseline (121.777 us; speedup 1.0000x reference)
//
#include <hip/hip_runtime.h>

typedef short short4v __attribute__((ext_vector_type(4)));
typedef short short8v __attribute__((ext_vector_type(8)));
typedef float float4v __attribute__((ext_vector_type(4)));
typedef unsigned short u16;

#define NB 2
#define NL 2048
#define NS 2048
#define NH 8
#define NE 64
#define HE (NH*NE)    // 512
#define NST (NS/64)   // 32 s-tiles
#define TILE_U16 4096 // one 64x64 bf16 tile image = 8 KB
#define HTILES 16     // s-tiles per half (S-split x2)
#define PHALF ((size_t)16*16*128*64)  // partial elems per half = 2,097,152

// pack two fp32 -> dword of two bf16 (round-to-nearest, half-up)
static __device__ __forceinline__ unsigned pk2bf(float a, float b) {
  union { float f; unsigned u; } x, y; x.f = a; y.f = b;
  return __builtin_amdgcn_perm(y.u + 0x8000u, x.u + 0x8000u, 0x07060302u);
}

#define GLD16(gp, lp) __builtin_amdgcn_global_load_lds( \
    (const __attribute__((address_space(1))) void*)(gp), \
    (__attribute__((address_space(3))) void*)(lp), 16, 0, 0)

// K-image swizzle hash: uses s bits {0,1,3} so the permuted QK row set
// (s = 8*(ln15>>2) + (ln15&3) + 4c) still spans all 8 chunk slots.
static __device__ __forceinline__ int fK(int s) { return (s & 3) | ((s >> 1) & 4); }

// ---------------------------------------------------------------------------
// Pre-pass: K,V fp32 -> bf16 tile images in d_ws, in the EXACT swizzled byte
// order the main kernel's LDS wants (K row-major, V transposed). K and V in
// separate blocks (1024 WGs, 4/CU) for latency overlap.
// ---------------------------------------------------------------------------
__global__ __launch_bounds__(256)
void prepack(const float* __restrict__ kp, const float* __restrict__ vp,
             u16* __restrict__ kimg, u16* __restrict__ vimg)
{
  __shared__ __align__(16) u16 ldsv[TILE_U16];

  const int bid  = blockIdx.x;          // 0..1023
  const int tile = bid >> 1;            // bh*NST + st
  const int doV  = bid & 1;
  const int st = tile & (NST - 1);
  const int bh = tile >> 5;
  const int h  = bh & (NH - 1);
  const int b  = bh >> 3;
  const int s0 = st * 64;
  const size_t base = (size_t)b * NS * HE + h * NE;
  const int tid  = threadIdx.x;
  const int wv   = tid >> 6;
  const int lane = tid & 63;
  const int ln7  = lane & 7;

  if (!doV) {
    u16* kt = kimg + (size_t)tile * TILE_U16;
    for (int slot = tid; slot < 512; slot += 256) {
      const int srow = slot >> 3, p = slot & 7, c = p ^ fK(srow);
      const float* src = kp + base + (size_t)(s0 + srow) * HE + c * 8;
      float4 x0 = *(const float4*)src;
      float4 x1 = *(const float4*)(src + 4);
      unsigned d[4] = { pk2bf(x0.x, x0.y), pk2bf(x0.z, x0.w),
                        pk2bf(x1.x, x1.y), pk2bf(x1.z, x1.w) };
      *(int4*)(kt + slot * 8) = *(const int4*)d;
    }
    return;
  }

  u16* vt = vimg + (size_t)tile * TILE_U16;
  {
    const float* vcol = vp + base + (size_t)(s0 + wv * 16) * HE + lane;
    unsigned vr[8];
    #pragma unroll
    for (int jj = 0; jj < 8; ++jj)
      vr[jj] = pk2bf(vcol[(size_t)(2 * jj) * HE], vcol[(size_t)(2 * jj + 1) * HE]);
    #pragma unroll
    for (int i = 0; i < 2; ++i) {
      const int cs = (2 * wv + i) ^ ln7;
      int4 t4 = make_int4((int)vr[4*i+0], (int)vr[4*i+1],
                          (int)vr[4*i+2], (int)vr[4*i+3]);
      *(int4*)(&ldsv[lane * 64 + cs * 8]) = t4;
    }
  }
  __syncthreads();
  {
    const int4* s = (const int4*)ldsv;
    int4* dst = (int4*)vt;
    dst[tid]       = s[tid];
    dst[tid + 256] = s[tid + 256];
  }
}

// ---------------------------------------------------------------------------
// Main: 256-thr WGs (4 waves — small independent blocks barrier-overlap best;
// R8's 8-wave blocks cost ~10 us of lockstep). S-split x2 cross-WG. ILP-2:
// each wave owns TWO 16-row l-subtiles (A: lbase, B: lbase+64) so every LDS
// K/V fragment read feeds 2x the MFMAs (halved LDS traffic & barriers per
// work) and each wave carries two independent dep chains. fp32 partials +
// separate XCD-matched reduce (no fences — R7 hazard).
// ---------------------------------------------------------------------------
__global__ __launch_bounds__(256, 2)
void assa_fwd(const float* __restrict__ qp, const u16* __restrict__ kimg,
              const u16* __restrict__ vimg, float* __restrict__ Apart,
              float* __restrict__ Dpart, float* __restrict__ Lpart)
{
  __shared__ __align__(16) u16 ldsb[2][2 * TILE_U16];  // [buf][K | V] 32 KB

  const int tid  = threadIdx.x;
  const int wv   = tid >> 6;
  const int lane = tid & 63;
  const int ln15 = lane & 15;
  const int ln7  = lane & 7;
  const int quad = lane >> 4;

  // bh in low 4 bits: all tiles of one (b,h) on one XCD
  const int bid  = blockIdx.x;        // 0..511
  const int bh   = bid & 15;
  const int rest = bid >> 4;          // 0..31
  const int lt   = rest & 15;         // 128-row l-tile
  const int half = rest >> 4;
  const int h    = bh & (NH - 1);
  const int b    = bh >> 3;

  const int lbA = lt * 128 + wv * 16;  // subtile A rows
  const int lbB = lbA + 64;            // subtile B rows

  // Q B-fragments for both subtiles, pre-scaled by 1/sqrt(64)
  short8v qA0, qA1, qB0, qB1;
  {
    const float* qr = qp + ((size_t)(b * NL + lbA + ln15)) * HE + h * NE + quad * 8;
    float4 q0 = *(const float4*)(qr);
    float4 q1 = *(const float4*)(qr + 4);
    float4 q2 = *(const float4*)(qr + 32);
    float4 q3 = *(const float4*)(qr + 36);
    unsigned d0[4] = { pk2bf(0.125f*q0.x, 0.125f*q0.y), pk2bf(0.125f*q0.z, 0.125f*q0.w),
                       pk2bf(0.125f*q1.x, 0.125f*q1.y), pk2bf(0.125f*q1.z, 0.125f*q1.w) };
    unsigned d1[4] = { pk2bf(0.125f*q2.x, 0.125f*q2.y), pk2bf(0.125f*q2.z, 0.125f*q2.w),
                       pk2bf(0.125f*q3.x, 0.125f*q3.y), pk2bf(0.125f*q3.z, 0.125f*q3.w) };
    qA0 = *(const short8v*)d0;
    qA1 = *(const short8v*)d1;
  }
  {
    const float* qr = qp + ((size_t)(b * NL + lbB + ln15)) * HE + h * NE + quad * 8;
    float4 q0 = *(const float4*)(qr);
    float4 q1 = *(const float4*)(qr + 4);
    float4 q2 = *(const float4*)(qr + 32);
    float4 q3 = *(const float4*)(qr + 36);
    unsigned d0[4] = { pk2bf(0.125f*q0.x, 0.125f*q0.y), pk2bf(0.125f*q0.z, 0.125f*q0.w),
                       pk2bf(0.125f*q1.x, 0.125f*q1.y), pk2bf(0.125f*q1.z, 0.125f*q1.w) };
    unsigned d1[4] = { pk2bf(0.125f*q2.x, 0.125f*q2.y), pk2bf(0.125f*q2.z, 0.125f*q2.w),
                       pk2bf(0.125f*q3.x, 0.125f*q3.y), pk2bf(0.125f*q3.z, 0.125f*q3.w) };
    qB0 = *(const short8v*)d0;
    qB1 = *(const short8v*)d1;
  }

  const size_t tbase = (size_t)bh * NST + half * HTILES;

  float4v aAs[4], aAd[4], aBs[4], aBd[4];
  #pragma unroll
  for (int t = 0; t < 4; ++t)
    #pragma unroll
    for (int r = 0; r < 4; ++r) {
      aAs[t][r] = 0.0f; aAd[t][r] = 0.0f;
      aBs[t][r] = 0.0f; aBd[t][r] = 0.0f;
    }

  float lA = 0.0f, lB = 0.0f;

  // DMA one tile (16 KB) into buffer nb: waves 0,1 -> K image, waves 2,3 -> V
  auto dma_tile = [&](int ti, int nb) {
    const int hf = wv & 1;
    const u16* g;
    u16* l;
    if (wv < 2) {
      g = kimg + (tbase + ti) * TILE_U16 + hf * 2048 + lane * 8;
      l = &ldsb[nb][hf * 2048];
    } else {
      g = vimg + (tbase + ti) * TILE_U16 + hf * 2048 + lane * 8;
      l = &ldsb[nb][TILE_U16 + hf * 2048];
    }
    GLD16(g,        l);
    GLD16(g +  512, l +  512);
    GLD16(g + 1024, l + 1024);
    GLD16(g + 1536, l + 1536);
  };

  dma_tile(0, 0);

  const int rperm = 8 * (ln15 >> 2) + (ln15 & 3);          // + 32U + 4c
  const int fk    = (ln15 & 3) | (((ln15 >> 2) & 1) << 2); // fK of that row

  for (int ti = 0; ti < HTILES; ++ti) {
    __builtin_amdgcn_s_waitcnt(0);
    __syncthreads();
    if (ti + 1 < HTILES) dma_tile(ti + 1, (ti + 1) & 1);

    const u16* kb_l = ldsb[ti & 1];
    const u16* vb_l = ldsb[ti & 1] + TILE_U16;

    #pragma unroll
    for (int U = 0; U < 2; ++U) {
      const u16* krow0 = &kb_l[(32 * U + rperm) * 64];
      const u16* krow1 = krow0 + 4 * 64;
      short8v kf00 = *(const short8v*)(krow0 + (quad ^ fk) * 8);
      short8v kf01 = *(const short8v*)(krow0 + ((4 + quad) ^ fk) * 8);
      short8v kf10 = *(const short8v*)(krow1 + (quad ^ fk) * 8);
      short8v kf11 = *(const short8v*)(krow1 + ((4 + quad) ^ fk) * 8);

      float4v sA0, sA1, sB0, sB1;
      #pragma unroll
      for (int r = 0; r < 4; ++r) { sA0[r]=0.f; sA1[r]=0.f; sB0[r]=0.f; sB1[r]=0.f; }
      sA0 = __builtin_amdgcn_mfma_f32_16x16x32_bf16(kf00, qA0, sA0, 0, 0, 0);
      sA0 = __builtin_amdgcn_mfma_f32_16x16x32_bf16(kf01, qA1, sA0, 0, 0, 0);
      sA1 = __builtin_amdgcn_mfma_f32_16x16x32_bf16(kf10, qA0, sA1, 0, 0, 0);
      sA1 = __builtin_amdgcn_mfma_f32_16x16x32_bf16(kf11, qA1, sA1, 0, 0, 0);
      sB0 = __builtin_amdgcn_mfma_f32_16x16x32_bf16(kf00, qB0, sB0, 0, 0, 0);
      sB0 = __builtin_amdgcn_mfma_f32_16x16x32_bf16(kf01, qB1, sB0, 0, 0, 0);
      sB1 = __builtin_amdgcn_mfma_f32_16x16x32_bf16(kf10, qB0, sB1, 0, 0, 0);
      sB1 = __builtin_amdgcn_mfma_f32_16x16x32_bf16(kf11, qB1, sB1, 0, 0, 0);

      short8v asA, adA, asB, adB;
      {
        float ps[8], pd[8];
        #pragma unroll
        for (int r = 0; r < 4; ++r) {
          float s0 = sA0[r], s1 = sA1[r];
          float r0 = s0 > 0.0f ? s0 : 0.0f;
          float r1 = s1 > 0.0f ? s1 : 0.0f;
          ps[r] = r0 * r0;  ps[4 + r] = r1 * r1;
          pd[r] = __expf(s0); pd[4 + r] = __expf(s1);
          lA += pd[r] + pd[4 + r];
        }
        unsigned da[4] = { pk2bf(ps[0], ps[1]), pk2bf(ps[2], ps[3]),
                           pk2bf(ps[4], ps[5]), pk2bf(ps[6], ps[7]) };
        unsigned db[4] = { pk2bf(pd[0], pd[1]), pk2bf(pd[2], pd[3]),
                           pk2bf(pd[4], pd[5]), pk2bf(pd[6], pd[7]) };
        asA = *(const short8v*)da;
        adA = *(const short8v*)db;
      }
      {
        float ps[8], pd[8];
        #pragma unroll
        for (int r = 0; r < 4; ++r) {
          float s0 = sB0[r], s1 = sB1[r];
          float r0 = s0 > 0.0f ? s0 : 0.0f;
          float r1 = s1 > 0.0f ? s1 : 0.0f;
          ps[r] = r0 * r0;  ps[4 + r] = r1 * r1;
          pd[r] = __expf(s0); pd[4 + r] = __expf(s1);
          lB += pd[r] + pd[4 + r];
        }
        unsigned da[4] = { pk2bf(ps[0], ps[1]), pk2bf(ps[2], ps[3]),
                           pk2bf(ps[4], ps[5]), pk2bf(ps[6], ps[7]) };
        unsigned db[4] = { pk2bf(pd[0], pd[1]), pk2bf(pd[2], pd[3]),
                           pk2bf(pd[4], pd[5]), pk2bf(pd[6], pd[7]) };
        asB = *(const short8v*)da;
        adB = *(const short8v*)db;
      }

      #pragma unroll
      for (int t = 0; t < 4; ++t) {
        short8v vf = *(const short8v*)(&vb_l[(t * 16 + ln15) * 64 +
                        (((4 * U + quad) ^ ln7) * 8)]);
        aAs[t] = __builtin_amdgcn_mfma_f32_16x16x32_bf16(asA, vf, aAs[t], 0, 0, 0);
        aAd[t] = __builtin_amdgcn_mfma_f32_16x16x32_bf16(adA, vf, aAd[t], 0, 0, 0);
        aBs[t] = __builtin_amdgcn_mfma_f32_16x16x32_bf16(asB, vf, aBs[t], 0, 0, 0);
        aBd[t] = __builtin_amdgcn_mfma_f32_16x16x32_bf16(adB, vf, aBd[t], 0, 0, 0);
      }
    }
  }

  lA += __shfl_xor(lA, 16, 64);
  lA += __shfl_xor(lA, 32, 64);
  lB += __shfl_xor(lB, 16, 64);
  lB += __shfl_xor(lB, 32, 64);

  // partials: [half][bh][lt][ll(128)][e(64)]
  float* Ab = Apart + half * PHALF + ((size_t)(bh * 16 + lt) * 128) * 64;
  float* Db = Dpart + half * PHALF + ((size_t)(bh * 16 + lt) * 128) * 64;
  #pragma unroll
  for (int t = 0; t < 4; ++t) {
    #pragma unroll
    for (int r = 0; r < 4; ++r) {
      const int llA = wv * 16 + quad * 4 + r;
      const int e   = t * 16 + ln15;
      Ab[llA * 64 + e]        = aAs[t][r];
      Db[llA * 64 + e]        = aAd[t][r];
      Ab[(llA + 64) * 64 + e] = aBs[t][r];
      Db[(llA + 64) * 64 + e] = aBd[t][r];
    }
  }
  if (quad == 0) {
    Lpart[(size_t)(half * 16 + bh) * NL + lbA + ln15] = lA;
    Lpart[(size_t)(half * 16 + bh) * NL + lbB + ln15] = lB;
  }
}

// ---------------------------------------------------------------------------
// Combine: out = al1*(A0+A1) + al2/(l0+l1)*(D0+D1). XCD-matched: bid&15 = bh,
// same swizzle as the writer, so partials are read on the XCD that wrote them.
// ---------------------------------------------------------------------------
__global__ __launch_bounds__(256)
void assa_reduce(const float* __restrict__ Apart, const float* __restrict__ Dpart,
                 const float* __restrict__ Lpart, const float* __restrict__ a1p,
                 const float* __restrict__ a2p, float* __restrict__ op)
{
  const int bid   = blockIdx.x;       // 0..2047
  const int bh    = bid & 15;
  const int rest  = bid >> 4;         // 0..127
  const int lt    = rest & 15;
  const int slice = rest >> 4;        // 0..7
  const int tid   = threadIdx.x;
  const int ll    = slice * 16 + (tid >> 4);
  const int e0    = (tid & 15) * 4;
  const int h = bh & 7, b = bh >> 3;
  const int l = lt * 128 + ll;

  const size_t pb = ((size_t)(bh * 16 + lt) * 128 + ll) * 64 + e0;
  float4 A0 = *(const float4*)(Apart + pb);
  float4 A1 = *(const float4*)(Apart + PHALF + pb);
  float4 D0 = *(const float4*)(Dpart + pb);
  float4 D1 = *(const float4*)(Dpart + PHALF + pb);
  const float l0 = Lpart[(size_t)bh * NL + l];
  const float l1 = Lpart[(size_t)(16 + bh) * NL + l];

  const float w1 = __expf(a1p[0]), w2 = __expf(a2p[0]);
  const float al1 = w1 / (w1 + w2);
  const float al2d = (w2 / (w1 + w2)) / (l0 + l1);

  float4 o;
  o.x = al1 * (A0.x + A1.x) + al2d * (D0.x + D1.x);
  o.y = al1 * (A0.y + A1.y) + al2d * (D0.y + D1.y);
  o.z = al1 * (A0.z + A1.z) + al2d * (D0.z + D1.z);
  o.w = al1 * (A0.w + A1.w) + al2d * (D0.w + D1.w);
  *(float4*)(op + ((size_t)(b * NL + l)) * HE + h * NE + e0) = o;
}

extern "C" void kernel_launch(void* const* d_in, const int* in_sizes, int n_in,
                              void* d_out, int out_size, void* d_ws, size_t ws_size,
                              hipStream_t stream) {
  const float* q  = (const float*)d_in[0];
  const float* k  = (const float*)d_in[1];
  const float* v  = (const float*)d_in[2];
  const float* a1 = (const float*)d_in[3];
  const float* a2 = (const float*)d_in[4];
  float* out = (float*)d_out;
  (void)in_sizes; (void)n_in; (void)out_size; (void)ws_size;

  u16* kimg = (u16*)d_ws;                                   // 4 MiB
  u16* vimg = kimg + (size_t)NB * NH * NST * TILE_U16;      // 4 MiB
  float* Apart = (float*)(vimg + (size_t)NB * NH * NST * TILE_U16); // 16 MiB
  float* Dpart = Apart + 2 * PHALF;                         // 16 MiB
  float* Lpart = Dpart + 2 * PHALF;                         // 256 KiB

  prepack<<<dim3(NB * NH * NST * 2), dim3(256), 0, stream>>>(k, v, kimg, vimg);
  assa_fwd<<<dim3(512), dim3(256), 0, stream>>>(q, kimg, vimg, Apart, Dpart, Lpart);
  assa_reduce<<<dim3(2048), dim3(256), 0, stream>>>(Apart, Dpart, Lpart, a1, a2, out);
}

// Round 11
// 111.539 us; speedup vs baseline: 1.0918x; 1.0918x over previous
//
#include <hip/hip_runtime.h>

typedef short short4v __attribute__((ext_vector_type(4)));
typedef short short8v __attribute__((ext_vector_type(8)));
typedef float float4v __attribute__((ext_vector_type(4)));
typedef unsigned short u16;

#define NB 2
#define NL 2048
#define NS 2048
#define NH 8
#define NE 64
#define HE (NH*NE)    // 512
#define NLT (NL/64)   // 32 l-tiles per (b,h)
#define NST (NS/64)   // 32 s-tiles
#define TILE_U16 4096 // one 64x64 bf16 tile image = 8 KB

// pack two fp32 -> dword of two bf16 (round-to-nearest, half-up)
static __device__ __forceinline__ unsigned pk2bf(float a, float b) {
  union { float f; unsigned u; } x, y; x.f = a; y.f = b;
  return __builtin_amdgcn_perm(y.u + 0x8000u, x.u + 0x8000u, 0x07060302u);
}

#define GLD16(gp, lp) __builtin_amdgcn_global_load_lds( \
    (const __attribute__((address_space(1))) void*)(gp), \
    (__attribute__((address_space(3))) void*)(lp), 16, 0, 0)

// K-image swizzle hash: uses s bits {0,1,3} so the permuted QK row set
// (s = 8*(ln15>>2) + (ln15&3) + 4c) still spans all 8 chunk slots.
static __device__ __forceinline__ int fK(int s) { return (s & 3) | ((s >> 1) & 4); }

// ---------------------------------------------------------------------------
// Pre-pass: K,V fp32 -> bf16 tile images in d_ws, in the EXACT swizzled byte
// order the main kernel's LDS wants (K row-major, V transposed). K and V in
// separate blocks (1024 WGs, 4/CU) for latency overlap.
// ---------------------------------------------------------------------------
__global__ __launch_bounds__(256)
void prepack(const float* __restrict__ kp, const float* __restrict__ vp,
             u16* __restrict__ kimg, u16* __restrict__ vimg)
{
  __shared__ __align__(16) u16 ldsv[TILE_U16];

  const int bid  = blockIdx.x;          // 0..1023
  const int tile = bid >> 1;            // bh*NST + st
  const int doV  = bid & 1;
  const int st = tile & (NST - 1);
  const int bh = tile >> 5;
  const int h  = bh & (NH - 1);
  const int b  = bh >> 3;
  const int s0 = st * 64;
  const size_t base = (size_t)b * NS * HE + h * NE;
  const int tid  = threadIdx.x;
  const int wv   = tid >> 6;
  const int lane = tid & 63;
  const int ln7  = lane & 7;

  if (!doV) {
    u16* kt = kimg + (size_t)tile * TILE_U16;
    for (int slot = tid; slot < 512; slot += 256) {
      const int srow = slot >> 3, p = slot & 7, c = p ^ fK(srow);
      const float* src = kp + base + (size_t)(s0 + srow) * HE + c * 8;
      float4 x0 = *(const float4*)src;
      float4 x1 = *(const float4*)(src + 4);
      unsigned d[4] = { pk2bf(x0.x, x0.y), pk2bf(x0.z, x0.w),
                        pk2bf(x1.x, x1.y), pk2bf(x1.z, x1.w) };
      *(int4*)(kt + slot * 8) = *(const int4*)d;
    }
    return;
  }

  u16* vt = vimg + (size_t)tile * TILE_U16;
  {
    const float* vcol = vp + base + (size_t)(s0 + wv * 16) * HE + lane;
    unsigned vr[8];
    #pragma unroll
    for (int jj = 0; jj < 8; ++jj)
      vr[jj] = pk2bf(vcol[(size_t)(2 * jj) * HE], vcol[(size_t)(2 * jj + 1) * HE]);
    #pragma unroll
    for (int i = 0; i < 2; ++i) {
      const int cs = (2 * wv + i) ^ ln7;
      int4 t4 = make_int4((int)vr[4*i+0], (int)vr[4*i+1],
                          (int)vr[4*i+2], (int)vr[4*i+3]);
      *(int4*)(&ldsv[lane * 64 + cs * 8]) = t4;
    }
  }
  __syncthreads();
  {
    const int4* s = (const int4*)ldsv;
    int4* dst = (int4*)vt;
    dst[tid]       = s[tid];
    dst[tid + 256] = s[tid + 256];
  }
}

// ---------------------------------------------------------------------------
// Main (bench-R6 verified structure, 42.9 us): one 256-thr WG = (b,h, 64-row
// l-tile), full S sweep, double-buffered LDS, DMA(st+1) in flight during
// compute(st). Row-permuted K=32 QK -> in-register relu^2/exp -> K=32 PV.
// NEW: softmax denominator computed on the MATRIX pipe via a ones-B MFMA
// (acc_l = ad8 x ones) — lands in exactly the epilogue C-layout row space
// (quad*4+r), deleting 16 VALU adds/tile/wave and the shuffle reduction.
// ---------------------------------------------------------------------------
__global__ __launch_bounds__(256, 2)
void assa_fwd(const float* __restrict__ qp, const u16* __restrict__ kimg,
              const u16* __restrict__ vimg, const float* __restrict__ a1p,
              const float* __restrict__ a2p, float* __restrict__ op)
{
  __shared__ __align__(16) u16 ldsb[2][2 * TILE_U16];  // [buf][K | V]

  const int tid  = threadIdx.x;
  const int wv   = tid >> 6;
  const int lane = tid & 63;
  const int ln15 = lane & 15;
  const int ln7  = lane & 7;
  const int quad = lane >> 4;

  // XCD swizzle: all 32 l-tiles of one (b,h) on one XCD
  const int bid = blockIdx.x;
  const int bh  = bid & 15;
  const int lt  = bid >> 4;
  const int h   = bh & (NH - 1);
  const int b   = bh >> 3;

  const int lbase = lt * 64 + wv * 16;

  // Q B-fragments, pre-scaled by 1/sqrt(64) (exact exponent shift)
  short8v qf0, qf1;
  {
    const float* qrow = qp + ((size_t)(b * NL + lbase + ln15)) * HE + h * NE + quad * 8;
    float4 q0 = *(const float4*)(qrow);
    float4 q1 = *(const float4*)(qrow + 4);
    float4 q2 = *(const float4*)(qrow + 32);
    float4 q3 = *(const float4*)(qrow + 36);
    unsigned d0[4] = { pk2bf(0.125f*q0.x, 0.125f*q0.y), pk2bf(0.125f*q0.z, 0.125f*q0.w),
                       pk2bf(0.125f*q1.x, 0.125f*q1.y), pk2bf(0.125f*q1.z, 0.125f*q1.w) };
    unsigned d1[4] = { pk2bf(0.125f*q2.x, 0.125f*q2.y), pk2bf(0.125f*q2.z, 0.125f*q2.w),
                       pk2bf(0.125f*q3.x, 0.125f*q3.y), pk2bf(0.125f*q3.z, 0.125f*q3.w) };
    qf0 = *(const short8v*)d0;
    qf1 = *(const short8v*)d1;
  }

  // ones B-fragment (bf16 1.0 in every slot) for the denominator MFMA
  short8v ones8;
  #pragma unroll
  for (int j = 0; j < 8; ++j) ones8[j] = (short)0x3F80;

  const size_t tbase = (size_t)bh * NST;

  float4v acc_s[4], acc_d[4], acc_l;
  #pragma unroll
  for (int t = 0; t < 4; ++t)
    #pragma unroll
    for (int r = 0; r < 4; ++r) { acc_s[t][r] = 0.0f; acc_d[t][r] = 0.0f; }
  #pragma unroll
  for (int r = 0; r < 4; ++r) acc_l[r] = 0.0f;

  // DMA one tile (16 KB) into buffer nb: waves 0,1 -> K image, waves 2,3 -> V
  auto dma_tile = [&](int st, int nb) {
    const int hf = wv & 1;
    const u16* g;
    u16* l;
    if (wv < 2) {
      g = kimg + (tbase + st) * TILE_U16 + hf * 2048 + lane * 8;
      l = &ldsb[nb][hf * 2048];
    } else {
      g = vimg + (tbase + st) * TILE_U16 + hf * 2048 + lane * 8;
      l = &ldsb[nb][TILE_U16 + hf * 2048];
    }
    GLD16(g,        l);
    GLD16(g +  512, l +  512);
    GLD16(g + 1024, l + 1024);
    GLD16(g + 1536, l + 1536);
  };

  dma_tile(0, 0);

  const int rperm = 8 * (ln15 >> 2) + (ln15 & 3);          // + 32U + 4c
  const int fk    = (ln15 & 3) | (((ln15 >> 2) & 1) << 2); // fK of that row

  for (int st = 0; st < NST; ++st) {
    __builtin_amdgcn_s_waitcnt(0);
    __syncthreads();
    if (st + 1 < NST) dma_tile(st + 1, (st + 1) & 1);

    const u16* kb_l = ldsb[st & 1];
    const u16* vb_l = ldsb[st & 1] + TILE_U16;

    #pragma unroll
    for (int U = 0; U < 2; ++U) {
      float4v sa0, sa1;
      #pragma unroll
      for (int r = 0; r < 4; ++r) { sa0[r] = 0.0f; sa1[r] = 0.0f; }
      const u16* krow0 = &kb_l[(32 * U + rperm) * 64];
      const u16* krow1 = krow0 + 4 * 64;
      short8v kf00 = *(const short8v*)(krow0 + (quad ^ fk) * 8);
      short8v kf01 = *(const short8v*)(krow0 + ((4 + quad) ^ fk) * 8);
      short8v kf10 = *(const short8v*)(krow1 + (quad ^ fk) * 8);
      short8v kf11 = *(const short8v*)(krow1 + ((4 + quad) ^ fk) * 8);
      sa0 = __builtin_amdgcn_mfma_f32_16x16x32_bf16(kf00, qf0, sa0, 0, 0, 0);
      sa0 = __builtin_amdgcn_mfma_f32_16x16x32_bf16(kf01, qf1, sa0, 0, 0, 0);
      sa1 = __builtin_amdgcn_mfma_f32_16x16x32_bf16(kf10, qf0, sa1, 0, 0, 0);
      sa1 = __builtin_amdgcn_mfma_f32_16x16x32_bf16(kf11, qf1, sa1, 0, 0, 0);
      // lane (quad,l=ln15): sa0[r] = score[s=32U+8q+r][l], sa1[r] = +4

      float ps[8], pd[8];
      #pragma unroll
      for (int r = 0; r < 4; ++r) {
        float s0 = sa0[r], s1 = sa1[r];
        float r0 = s0 > 0.0f ? s0 : 0.0f;
        float r1 = s1 > 0.0f ? s1 : 0.0f;
        ps[r] = r0 * r0;  ps[4 + r] = r1 * r1;
        pd[r] = __expf(s0); pd[4 + r] = __expf(s1);
      }
      unsigned da[4] = { pk2bf(ps[0], ps[1]), pk2bf(ps[2], ps[3]),
                         pk2bf(ps[4], ps[5]), pk2bf(ps[6], ps[7]) };
      unsigned db[4] = { pk2bf(pd[0], pd[1]), pk2bf(pd[2], pd[3]),
                         pk2bf(pd[4], pd[5]), pk2bf(pd[6], pd[7]) };
      short8v as8 = *(const short8v*)da;   // A[m=l][k=s-32U] for K=32 PV
      short8v ad8 = *(const short8v*)db;

      // denominator on the matrix pipe: acc_l[r] += sum_s pd[row=quad*4+r][s]
      acc_l = __builtin_amdgcn_mfma_f32_16x16x32_bf16(ad8, ones8, acc_l, 0, 0, 0);

      #pragma unroll
      for (int t = 0; t < 4; ++t) {
        short8v vf = *(const short8v*)(&vb_l[(t * 16 + ln15) * 64 +
                        (((4 * U + quad) ^ ln7) * 8)]);
        acc_s[t] = __builtin_amdgcn_mfma_f32_16x16x32_bf16(as8, vf, acc_s[t], 0, 0, 0);
        acc_d[t] = __builtin_amdgcn_mfma_f32_16x16x32_bf16(ad8, vf, acc_d[t], 0, 0, 0);
      }
    }
  }

  const float w1 = __expf(a1p[0]), w2 = __expf(a2p[0]);
  const float al1 = w1 / (w1 + w2);
  const float al2 = w2 / (w1 + w2);

  // acc_l[r] is the full denominator for row quad*4+r (identical across cols)
  float c_d[4];
  #pragma unroll
  for (int r = 0; r < 4; ++r) c_d[r] = al2 / acc_l[r];

  #pragma unroll
  for (int t = 0; t < 4; ++t) {
    #pragma unroll
    for (int r = 0; r < 4; ++r) {
      float val = al1 * acc_s[t][r] + c_d[r] * acc_d[t][r];
      const int l = lbase + quad * 4 + r;
      const int e = t * 16 + ln15;
      op[((size_t)(b * NL + l)) * HE + h * NE + e] = val;
    }
  }
}

extern "C" void kernel_launch(void* const* d_in, const int* in_sizes, int n_in,
                              void* d_out, int out_size, void* d_ws, size_t ws_size,
                              hipStream_t stream) {
  const float* q  = (const float*)d_in[0];
  const float* k  = (const float*)d_in[1];
  const float* v  = (const float*)d_in[2];
  const float* a1 = (const float*)d_in[3];
  const float* a2 = (const float*)d_in[4];
  float* out = (float*)d_out;
  (void)in_sizes; (void)n_in; (void)out_size; (void)ws_size;

  u16* kimg = (u16*)d_ws;                                   // 4 MiB
  u16* vimg = kimg + (size_t)NB * NH * NST * TILE_U16;      // 4 MiB

  prepack<<<dim3(NB * NH * NST * 2), dim3(256), 0, stream>>>(k, v, kimg, vimg);
  assa_fwd<<<dim3(NB * NH * NLT), dim3(256), 0, stream>>>(q, kimg, vimg, a1, a2, out);
}